// Round 7
// baseline (365.368 us; speedup 1.0000x reference)
//
#include <hip/hip_runtime.h>
#include <hip/hip_fp16.h>

#define HC 128      // H*C
#define NHEAD 4
#define NEG 0.2f
#define GEPS 1e-16f
#define BSH 9       // bucket = dst >> 9 (512 nodes/bucket); nbuck<=256 required
#define TILE 4096   // edges per partA block

typedef __bf16 bf16x8 __attribute__((ext_vector_type(8)));
typedef float  f32x4  __attribute__((ext_vector_type(4)));

__device__ __forceinline__ unsigned int bf16rn(float f) {
  unsigned int u = __float_as_uint(f);
  return (u + 0x7fffu + ((u >> 16) & 1u)) >> 16;
}

// K0: transpose W (fp32 [k][n]) -> wtg (bf16 [n][k]) once; zero bcnt.
__global__ __launch_bounds__(256) void k_prep(const float* __restrict__ W,
                                              unsigned short* __restrict__ wtg,
                                              int* __restrict__ bcnt) {
  int o = blockIdx.x * 256 + threadIdx.x;   // grid 64 -> 16384
  int n = o >> 7, k = o & 127;
  wtg[o] = (unsigned short)bf16rn(W[k * HC + n]);
  if (blockIdx.x == 0) bcnt[threadIdx.x] = 0;
}

// K1: h = x @ W via MFMA bf16 (fp32 accum). 128 rows/block, 4 waves; wave w
// covers rows [w*32, w*32+32) = 2 m-tiles x 8 n-tiles, K=128 in 4 chunks.
// Epilogue: logits from fp32 accumulators -> exp-pairs; LDS bounce -> packed
// bf16 hb with coalesced stores.
// Frag layouts (HW-verified, learn_hip m89/m91/m120): A[m=lane&15][k=quad*8+j],
// B[k=quad*8+j][n=lane&15], C/D[row=quad*4+reg][col=lane&15].
__global__ __launch_bounds__(256) void k_proj(const float* __restrict__ x,
                                              const unsigned short* __restrict__ wtg,
                                              const float* __restrict__ att_src,
                                              const float* __restrict__ att_dst,
                                              unsigned int* __restrict__ hb,
                                              float2* __restrict__ easrc,
                                              float2* __restrict__ eadst, int N) {
  __shared__ union {
    unsigned short wt[128 * 136];   // B-tile, padded stride 136 u16 (=272B, 16B-aligned)
    unsigned int bb[128 * 65];      // epilogue bounce (reused after K-loop)
  } sm;
  const int t = threadIdx.x;
  const int row0 = blockIdx.x * 128;
  // stage Wt (bf16) into LDS
  for (int i = t; i < 2048; i += 256) {
    uint4 v = *(const uint4*)(wtg + i * 8);
    int n = (i * 8) >> 7, k = (i * 8) & 127;
    *(uint4*)(sm.wt + n * 136 + k) = v;
  }
  __syncthreads();
  const int w = t >> 6;            // wave 0..3
  const int l = t & 63;
  const int q = l >> 4, c = l & 15;

  f32x4 acc[2][8];
#pragma unroll
  for (int mt = 0; mt < 2; ++mt)
#pragma unroll
    for (int nt = 0; nt < 8; ++nt) {
      f32x4 z = {0.f, 0.f, 0.f, 0.f};
      acc[mt][nt] = z;
    }

  for (int kc = 0; kc < 4; ++kc) {
    bf16x8 a[2];
#pragma unroll
    for (int mt = 0; mt < 2; ++mt) {
      int gRow = row0 + w * 32 + mt * 16 + c;
      gRow = min(gRow, N - 1);
      const float4* xp = (const float4*)(x + (size_t)gRow * HC + kc * 32 + q * 8);
      float4 f0 = xp[0], f1 = xp[1];
      a[mt][0] = (__bf16)f0.x; a[mt][1] = (__bf16)f0.y;
      a[mt][2] = (__bf16)f0.z; a[mt][3] = (__bf16)f0.w;
      a[mt][4] = (__bf16)f1.x; a[mt][5] = (__bf16)f1.y;
      a[mt][6] = (__bf16)f1.z; a[mt][7] = (__bf16)f1.w;
    }
#pragma unroll
    for (int nt = 0; nt < 8; ++nt) {
      uint4 bu = *(const uint4*)(sm.wt + (nt * 16 + c) * 136 + kc * 32 + q * 8);
      bf16x8 bfr = __builtin_bit_cast(bf16x8, bu);
      acc[0][nt] = __builtin_amdgcn_mfma_f32_16x16x32_bf16(a[0], bfr, acc[0][nt], 0, 0, 0);
      acc[1][nt] = __builtin_amdgcn_mfma_f32_16x16x32_bf16(a[1], bfr, acc[1][nt], 0, 0, 0);
    }
  }

  // logits from fp32 accumulators (pre-rounding)
  float asc[4][2], adc[4][2];
#pragma unroll
  for (int h = 0; h < 4; ++h)
#pragma unroll
    for (int p = 0; p < 2; ++p) {
      asc[h][p] = att_src[h * 32 + p * 16 + c];
      adc[h][p] = att_dst[h * 32 + p * 16 + c];
    }
#pragma unroll
  for (int mt = 0; mt < 2; ++mt)
#pragma unroll
    for (int h = 0; h < 4; ++h)
#pragma unroll
      for (int r = 0; r < 4; ++r) {
        float as_ = acc[mt][2 * h][r] * asc[h][0] + acc[mt][2 * h + 1][r] * asc[h][1];
        float ad_ = acc[mt][2 * h][r] * adc[h][0] + acc[mt][2 * h + 1][r] * adc[h][1];
#pragma unroll
        for (int off = 1; off < 16; off <<= 1) {
          as_ += __shfl_xor(as_, off);
          ad_ += __shfl_xor(ad_, off);
        }
        if (c == 0) {
          int gRow = row0 + w * 32 + mt * 16 + q * 4 + r;
          if (gRow < N) {
            easrc[gRow * NHEAD + h] = make_float2(__expf(as_), __expf(NEG * as_));
            eadst[gRow * NHEAD + h] = make_float2(__expf(ad_), __expf(NEG * ad_));
          }
        }
      }

  // bounce C -> LDS (packed bf16 pairs via lane-pair shfl), coalesced store
  __syncthreads();   // all waves done reading sm.wt
#pragma unroll
  for (int mt = 0; mt < 2; ++mt)
#pragma unroll
    for (int nt = 0; nt < 8; ++nt)
#pragma unroll
      for (int r = 0; r < 4; ++r) {
        unsigned int me = bf16rn(acc[mt][nt][r]);
        unsigned int pr = (unsigned int)__shfl_xor((int)me, 1);
        if ((l & 1) == 0) {
          int row = w * 32 + mt * 16 + q * 4 + r;
          int cp = (c >> 1) + nt * 8;
          sm.bb[row * 65 + cp] = me | (pr << 16);
        }
      }
  __syncthreads();
  for (int i = t; i < 8192; i += 256) {
    int row = i >> 6, col = i & 63;
    int gRow = row0 + row;
    if (gRow < N) hb[(size_t)gRow * 64 + col] = sm.bb[row * 65 + col];
  }
}

// K2: bucket histogram (LDS-staged)
__global__ __launch_bounds__(256) void k_bcount(const int* __restrict__ dst,
                                                int* __restrict__ bcnt, int E) {
  __shared__ int hist[256];
  int t = threadIdx.x;
  hist[t] = 0;
  __syncthreads();
  for (int e = blockIdx.x * 256 + t; e < E; e += gridDim.x * 256)
    atomicAdd(&hist[dst[e] >> BSH], 1);
  __syncthreads();
  if (hist[t]) atomicAdd(&bcnt[t], hist[t]);
}

// K3: scan bucket counts -> bbase[nbuck+1], cursor copy; rowptr[N]=E
__global__ __launch_bounds__(256) void k_bscan(const int* __restrict__ bcnt,
                                               int* __restrict__ bbase,
                                               int* __restrict__ bcur,
                                               int* __restrict__ rowptr,
                                               int nbuck, int N, int E) {
  __shared__ int ss[256];
  int t = threadIdx.x;
  int v = (t < nbuck) ? bcnt[t] : 0;
  int x = v;
  ss[t] = x;
  __syncthreads();
  for (int off = 1; off < 256; off <<= 1) {
    int y = (t >= off) ? ss[t - off] : 0;
    __syncthreads();
    x += y;
    ss[t] = x;
    __syncthreads();
  }
  if (t < nbuck) {
    bbase[t] = x - v;
    bcur[t] = x - v;
  }
  if (t == 0) {
    bbase[nbuck] = E;
    rowptr[N] = E;
  }
}

// K4: radix-partition edges into bucket regions of ebuf.
// Packed entry: (src << 9) | (dst & 511) -- src < 2^17, fits 26 bits.
__global__ __launch_bounds__(256) void k_partA(const int* __restrict__ src,
                                               const int* __restrict__ dst,
                                               int* __restrict__ bcur,
                                               unsigned int* __restrict__ ebuf,
                                               int E, int nbuck) {
  __shared__ unsigned int stage[TILE];
  __shared__ unsigned char bkt[TILE];
  __shared__ int hist[256], loff[256], lcur[256], gbase[256], ss[256];
  int t = threadIdx.x;
  int e0 = blockIdx.x * TILE;
  int cnt = min(TILE, E - e0);
  hist[t] = 0;
  __syncthreads();
  for (int i = t; i < cnt; i += 256)
    atomicAdd(&hist[dst[e0 + i] >> BSH], 1);
  __syncthreads();
  int v = hist[t];
  int x = v;
  ss[t] = x;
  __syncthreads();
  for (int off = 1; off < 256; off <<= 1) {
    int y = (t >= off) ? ss[t - off] : 0;
    __syncthreads();
    x += y;
    ss[t] = x;
    __syncthreads();
  }
  loff[t] = x - v;
  lcur[t] = x - v;
  __syncthreads();
  for (int i = t; i < cnt; i += 256) {
    int d = dst[e0 + i];
    int s = src[e0 + i];
    int b = d >> BSH;
    int r = atomicAdd(&lcur[b], 1);
    stage[r] = ((unsigned int)s << BSH) | (unsigned int)(d & ((1 << BSH) - 1));
    bkt[r] = (unsigned char)b;
  }
  __syncthreads();
  if (t < nbuck) {
    int cta = lcur[t] - loff[t];
    gbase[t] = cta ? atomicAdd(&bcur[t], cta) : 0;
  }
  __syncthreads();
  for (int i = t; i < cnt; i += 256) {
    int b = bkt[i];
    ebuf[gbase[b] + (i - loff[b])] = stage[i];
  }
}

// K5: per-bucket exact placement (512 threads) + per-edge softmax coefficient
// (4 heads, fp16-packed uint2). eadst slice staged in LDS; scatter windows are
// CU-local. Also writes rowptr slice.
__global__ __launch_bounds__(512) void k_partB(const unsigned int* __restrict__ ebuf,
                                               const int* __restrict__ bbase,
                                               const float2* __restrict__ easrc,
                                               const float2* __restrict__ eadst,
                                               int* __restrict__ rowptr,
                                               int* __restrict__ srcidx,
                                               uint2* __restrict__ excoef, int N) {
  __shared__ int lcnt[512], ss[512];
  __shared__ float4 eds[512][2];
  int b = blockIdx.x;
  int t = threadIdx.x;
  int beg = bbase[b], end = bbase[b + 1];
  lcnt[t] = 0;
  int node = (b << BSH) + t;
  if (node < N) {
    const float4* ep = (const float4*)(eadst + node * NHEAD);
    eds[t][0] = ep[0];
    eds[t][1] = ep[1];
  }
  __syncthreads();
  for (int j = beg + t; j < end; j += 512)
    atomicAdd(&lcnt[ebuf[j] & 511], 1);
  __syncthreads();
  int v = lcnt[t];
  int x = v;
  ss[t] = x;
  __syncthreads();
  for (int off = 1; off < 512; off <<= 1) {
    int y = (t >= off) ? ss[t - off] : 0;
    __syncthreads();
    x += y;
    ss[t] = x;
    __syncthreads();
  }
  int ex0 = x - v;
  if (node < N) rowptr[node] = beg + ex0;
  __syncthreads();
  lcnt[t] = ex0;     // cursor
  __syncthreads();
  for (int j = beg + t; j < end; j += 512) {
    unsigned int v2 = ebuf[j];
    int doff = v2 & 511;
    int s = (int)(v2 >> BSH);
    int pos = beg + atomicAdd(&lcnt[doff], 1);
    const float4* sp = (const float4*)(easrc + s * NHEAD);
    float4 es01 = sp[0], es23 = sp[1];
    float4 ed01 = eds[doff][0], ed23 = eds[doff][1];
    float e0 = fmaxf(es01.x * ed01.x, es01.y * ed01.y);
    float e1 = fmaxf(es01.z * ed01.z, es01.w * ed01.w);
    float e2 = fmaxf(es23.x * ed23.x, es23.y * ed23.y);
    float e3 = fmaxf(es23.z * ed23.z, es23.w * ed23.w);
    unsigned int lo = (unsigned int)__half_as_ushort(__float2half(e0)) |
                      ((unsigned int)__half_as_ushort(__float2half(e1)) << 16);
    unsigned int hi = (unsigned int)__half_as_ushort(__float2half(e2)) |
                      ((unsigned int)__half_as_ushort(__float2half(e3)) << 16);
    srcidx[pos] = s;
    excoef[pos] = make_uint2(lo, hi);
  }
}

// K6: aggregation. Streams srcidx+excoef sequentially; only hb is gathered.
__global__ __launch_bounds__(256) void k_agg(const int* __restrict__ rowptr,
                                             const int* __restrict__ srcidx,
                                             const uint2* __restrict__ excoef,
                                             const unsigned int* __restrict__ hb,
                                             const float2* __restrict__ easrc,
                                             const float2* __restrict__ eadst,
                                             const float* __restrict__ bias,
                                             float* __restrict__ out, int N) {
  int n = blockIdx.x * 4 + (threadIdx.x >> 6);
  if (n >= N) return;
  int lane = threadIdx.x & 63;
  int head = lane >> 4;
  float2 ed = eadst[n * NHEAD + head];
  float2 es = easrc[n * NHEAD + head];
  float exs = fmaxf(es.x * ed.x, es.y * ed.y);   // self-loop
  unsigned int u = hb[(size_t)n * 64 + lane];
  float accx = __uint_as_float(u << 16) * exs;
  float accy = __uint_as_float(u & 0xffff0000u) * exs;
  float ssum = exs;

  int beg = rowptr[n], end = rowptr[n + 1];
  int si1 = 0, si2 = 0;
  unsigned int uv1 = 0;
  uint2 ec1 = make_uint2(0, 0);
  if (beg < end) {
    si1 = srcidx[beg];
    uv1 = hb[(size_t)si1 * 64 + lane];
    ec1 = excoef[beg];
    si2 = srcidx[(beg + 1 < end) ? beg + 1 : beg];
  }
  for (int j = beg; j < end; ++j) {
    unsigned int uv0 = uv1;
    uint2 ec0 = ec1;
    si1 = si2;
    si2 = srcidx[(j + 2 < end) ? j + 2 : j];
    int jn = (j + 1 < end) ? j + 1 : j;
    ec1 = excoef[jn];
    uv1 = hb[(size_t)si1 * 64 + lane];
    unsigned int wsel = (head & 2) ? ec0.y : ec0.x;
    unsigned short hu = (head & 1) ? (unsigned short)(wsel >> 16)
                                   : (unsigned short)(wsel & 0xffffu);
    float ex = __half2float(__ushort_as_half(hu));
    accx = fmaf(__uint_as_float(uv0 << 16), ex, accx);
    accy = fmaf(__uint_as_float(uv0 & 0xffff0000u), ex, accy);
    ssum += ex;
  }
  float inv = 1.0f / (ssum + GEPS);
  float2 bv = *(const float2*)(bias + lane * 2);
  *(float2*)(out + (size_t)n * HC + lane * 2) =
      make_float2(fmaf(accx, inv, bv.x), fmaf(accy, inv, bv.y));
}

extern "C" void kernel_launch(void* const* d_in, const int* in_sizes, int n_in,
                              void* d_out, int out_size, void* d_ws, size_t ws_size,
                              hipStream_t stream) {
  const float* x       = (const float*)d_in[0];
  const int*   ei      = (const int*)d_in[1];   // int32 (JAX x64-disabled)
  const float* W       = (const float*)d_in[2];
  const float* att_src = (const float*)d_in[3];
  const float* att_dst = (const float*)d_in[4];
  const float* bias    = (const float*)d_in[5];
  float* out = (float*)d_out;

  const int N = in_sizes[0] / HC;
  const int E = in_sizes[1] / 2;
  const int* src = ei;
  const int* dst = ei + E;
  const int nbuck = (N + (1 << BSH) - 1) >> BSH;   // 196 for N=100K (<=256)

  // ws (ints): hb 64N | easrc 8N f | eadst 8N f | rowptr N+4 | srcidx E
  //            | ebuf E | excoef 2E | wtg 8192 | bcnt 256 | bbase 257 | bcur 256
  // ~58 MB. All offsets keep 16B alignment for the float4/uint4 casts.
  unsigned int* hb = (unsigned int*)d_ws;
  float2* easrc = (float2*)(hb + (size_t)N * 64);
  float2* eadst = easrc + (size_t)N * NHEAD;
  int* rowptr = (int*)(eadst + (size_t)N * NHEAD);
  int* srcidx = rowptr + (N + 4);
  unsigned int* ebuf = (unsigned int*)(srcidx + E);
  uint2* excoef = (uint2*)(ebuf + E);
  unsigned short* wtg = (unsigned short*)(excoef + E);
  int* bcnt = (int*)(wtg + 16384);
  int* bbase = bcnt + 256;
  int* bcur = bbase + 257;

  k_prep<<<64, 256, 0, stream>>>(W, wtg, bcnt);
  k_proj<<<(N + 127) / 128, 256, 0, stream>>>(x, wtg, att_src, att_dst, hb, easrc, eadst, N);
  k_bcount<<<1024, 256, 0, stream>>>(dst, bcnt, E);
  k_bscan<<<1, 256, 0, stream>>>(bcnt, bbase, bcur, rowptr, nbuck, N, E);
  k_partA<<<(E + TILE - 1) / TILE, 256, 0, stream>>>(src, dst, bcur, ebuf, E, nbuck);
  k_partB<<<nbuck, 512, 0, stream>>>(ebuf, bbase, easrc, eadst, rowptr, srcidx, excoef, N);
  k_agg<<<(N + 3) / 4, 256, 0, stream>>>(rowptr, srcidx, excoef, hb, easrc, eadst, bias, out, N);
}